// Round 1
// baseline (235.522 us; speedup 1.0000x reference)
//
#include <hip/hip_runtime.h>
#include <hip/hip_bf16.h>

#define T_DIM 2048
#define B_DIM 4
#define C_DIM 1024
#define H_DIM 16
#define K_DIM 7
#define HK    112      // H*K
#define KB    32       // C/32 k-blocks
#define TT    16       // t-chunk per conv block

typedef float f32x4 __attribute__((ext_vector_type(4)));
typedef short s16x8 __attribute__((ext_vector_type(8)));

// f32 -> bf16 (round-to-nearest-even), as raw short
__device__ __forceinline__ short f2bf(float f) {
    union { float f; unsigned u; } v; v.f = f;
    return (short)((v.u + 0x7FFFu + ((v.u >> 16) & 1u)) >> 16);
}

// ---------------- Kernel 1: logits GEMM (bf16 MFMA) + softmax -> wt ----------------
// Grid: 512 blocks (16 rows of the flattened (T*B, C) x-matrix each), 256 threads.
// Wave w handles n-tiles {2w, 2w+1} (wave 3: only tile 6). A-frags loaded from
// global per wave (L1-shared across waves); W k-slice staged in LDS as bf16.
__global__ __launch_bounds__(256, 2) void k_logits(const float* __restrict__ x,
                                                   const float* __restrict__ W,
                                                   float* __restrict__ wt) {
    // stride 40 shorts = 80B rows: 16B-aligned (ds_read_b128 ok), bank period
    // o*20 mod 32 -> only 2-way aliasing across 16 lanes (free).
    __shared__ short w_lds[HK][40];
    __shared__ float sm[16][113];

    const int tid  = (int)threadIdx.x;
    const int lane = tid & 63;
    const int wid  = tid >> 6;
    const int m0   = (int)blockIdx.x * 16;

    const int nt0   = wid * 2;
    const bool has2 = (wid < 3);

    const int cl   = lane & 15;          // row within A-tile / col within B-tile
    const int koff = (lane >> 4) * 8;    // k offset of this lane's 8 contiguous elems

    const float* aptr = x + (size_t)(m0 + cl) * C_DIM + koff;

    f32x4 acc0 = {0.f, 0.f, 0.f, 0.f};
    f32x4 acc1 = {0.f, 0.f, 0.f, 0.f};

    for (int kb = 0; kb < KB; ++kb) {
        // A load issued early (independent of LDS staging below)
        f32x4 a0 = *(const f32x4*)(aptr + kb * 32);
        f32x4 a1 = *(const f32x4*)(aptr + kb * 32 + 4);

        // stage W[:, kb*32 : kb*32+32] as bf16 into LDS (3584 elems, 14/thread)
        for (int i = tid; i < HK * 32; i += 256) {
            int o = i >> 5, kk = i & 31;
            w_lds[o][kk] = f2bf(W[o * C_DIM + kb * 32 + kk]);
        }
        __syncthreads();

        s16x8 afr;
        afr[0] = f2bf(a0[0]); afr[1] = f2bf(a0[1]); afr[2] = f2bf(a0[2]); afr[3] = f2bf(a0[3]);
        afr[4] = f2bf(a1[0]); afr[5] = f2bf(a1[1]); afr[6] = f2bf(a1[2]); afr[7] = f2bf(a1[3]);

        s16x8 b0 = *(const s16x8*)&w_lds[nt0 * 16 + cl][koff];
        acc0 = __builtin_amdgcn_mfma_f32_16x16x32_bf16(afr, b0, acc0, 0, 0, 0);
        if (has2) {
            s16x8 b1 = *(const s16x8*)&w_lds[(nt0 + 1) * 16 + cl][koff];
            acc1 = __builtin_amdgcn_mfma_f32_16x16x32_bf16(afr, b1, acc1, 0, 0, 0);
        }
        __syncthreads();  // before next iteration overwrites w_lds
    }

    // scatter logits to LDS: D layout col=lane&15, row=(lane>>4)*4 + reg  [m89]
    const int r0 = (lane >> 4) * 4;
    #pragma unroll
    for (int j = 0; j < 4; ++j) sm[r0 + j][nt0 * 16 + cl] = acc0[j];
    if (has2) {
        #pragma unroll
        for (int j = 0; j < 4; ++j) sm[r0 + j][(nt0 + 1) * 16 + cl] = acc1[j];
    }
    __syncthreads();

    // softmax over K=7: 256 tasks = 16 rows x 16 heads, one per thread
    const int r = tid >> 4, h = tid & 15;
    float v[K_DIM];
    float mx = -1e30f;
    #pragma unroll
    for (int k = 0; k < K_DIM; ++k) { v[k] = sm[r][h * K_DIM + k]; mx = fmaxf(mx, v[k]); }
    float s = 0.f;
    #pragma unroll
    for (int k = 0; k < K_DIM; ++k) { v[k] = __expf(v[k] - mx); s += v[k]; }
    const float inv = 1.f / s;
    float* wrow = wt + (size_t)(m0 + r) * HK + h * K_DIM;
    #pragma unroll
    for (int k = 0; k < K_DIM; ++k) wrow[k] = v[k] * inv;
}

// ---------------- Kernel 2: causal dynamic conv (register rolling window) ----------
// Block = (t-chunk of TT, batch b); 256 threads x float4 = all 1024 channels.
// Thread keeps x[t-6..t-1] for its 4 channels in registers; x read once + halo.
__global__ __launch_bounds__(256) void k_conv(const float* __restrict__ x,
                                              const float* __restrict__ wt,
                                              const float* __restrict__ bias,
                                              float* __restrict__ out) {
    const int tid = (int)threadIdx.x;
    const int b   = (int)blockIdx.y;
    const int t0  = (int)blockIdx.x * TT;
    const int c4  = tid * 4;
    const int h   = tid >> 4;   // (tid*4)/64

    const f32x4 bias4 = *(const f32x4*)(bias + c4);

    f32x4 win[6];
    #pragma unroll
    for (int k = 0; k < 6; ++k) {
        const int t = t0 - 6 + k;
        if (t >= 0) win[k] = *(const f32x4*)(x + ((size_t)t * B_DIM + b) * C_DIM + c4);
        else        win[k] = (f32x4){0.f, 0.f, 0.f, 0.f};
    }

    #pragma unroll
    for (int tt = 0; tt < TT; ++tt) {
        const int t = t0 + tt;
        const size_t row = (size_t)t * B_DIM + b;
        const f32x4 xv = *(const f32x4*)(x + row * C_DIM + c4);
        const float* wrow = wt + row * HK + h * K_DIM;

        f32x4 o = bias4;
        o += win[0] * wrow[0];
        o += win[1] * wrow[1];
        o += win[2] * wrow[2];
        o += win[3] * wrow[3];
        o += win[4] * wrow[4];
        o += win[5] * wrow[5];
        o += xv     * wrow[6];
        *(f32x4*)(out + row * C_DIM + c4) = o;

        win[0] = win[1]; win[1] = win[2]; win[2] = win[3];
        win[3] = win[4]; win[4] = win[5]; win[5] = xv;
    }
}

extern "C" void kernel_launch(void* const* d_in, const int* in_sizes, int n_in,
                              void* d_out, int out_size, void* d_ws, size_t ws_size,
                              hipStream_t stream) {
    const float* x    = (const float*)d_in[0];
    const float* W    = (const float*)d_in[1];
    const float* bias = (const float*)d_in[2];
    float* out = (float*)d_out;
    float* wt  = (float*)d_ws;   // (T*B, 112) f32 = 3.67 MB scratch

    k_logits<<<dim3((T_DIM * B_DIM) / 16), 256, 0, stream>>>(x, W, wt);
    k_conv<<<dim3(T_DIM / TT, B_DIM), 256, 0, stream>>>(x, wt, bias, out);
}

// Round 2
// 107.490 us; speedup vs baseline: 2.1911x; 2.1911x over previous
//
#include <hip/hip_runtime.h>
#include <hip/hip_bf16.h>

#define T_DIM 2048
#define B_DIM 4
#define C_DIM 1024
#define H_DIM 16
#define K_DIM 7
#define HK    112      // H*K
#define TT    16       // t-chunk per conv block

typedef float f32x4 __attribute__((ext_vector_type(4)));
typedef short s16x8 __attribute__((ext_vector_type(8)));

// f32 -> bf16 (round-to-nearest-even), as raw short
__device__ __forceinline__ short f2bf(float f) {
    union { float f; unsigned u; } v; v.f = f;
    return (short)((v.u + 0x7FFFu + ((v.u >> 16) & 1u)) >> 16);
}
__device__ __forceinline__ float bf2f(unsigned short s) {
    union { unsigned u; float f; } v; v.u = ((unsigned)s) << 16; return v.f;
}

// ---------------- Kernel 0: W f32 -> bf16 (112*1024 elems, 56 blocks) -----------
__global__ void k_cvtW(const float* __restrict__ W, short* __restrict__ Wb) {
    const int i = ((int)blockIdx.x * 256 + (int)threadIdx.x) * 8;
    f32x4 a = *(const f32x4*)(W + i);
    f32x4 b = *(const f32x4*)(W + i + 4);
    s16x8 o;
    o[0] = f2bf(a[0]); o[1] = f2bf(a[1]); o[2] = f2bf(a[2]); o[3] = f2bf(a[3]);
    o[4] = f2bf(b[0]); o[5] = f2bf(b[1]); o[6] = f2bf(b[2]); o[7] = f2bf(b[3]);
    *(s16x8*)(Wb + i) = o;
}

// ---------------- Kernel 1: logits GEMM (bf16 MFMA) + softmax -> wt (bf16) -------
// Grid 512 blocks = one 16-row m-tile each; 4 waves split K (8 k-blocks of 32
// each). B-fragments read straight from global bf16 W (L1/L2-resident) — no
// LDS staging, no K-loop barriers. Partials combined in LDS, fused softmax.
__global__ __launch_bounds__(256, 2) void k_logits(const float* __restrict__ x,
                                                   const short* __restrict__ Wb,
                                                   unsigned short* __restrict__ wt) {
    __shared__ float sm[4][16][113];

    const int tid  = (int)threadIdx.x;
    const int lane = tid & 63;
    const int wid  = tid >> 6;
    const int m0   = (int)blockIdx.x * 16;

    const int cl   = lane & 15;          // A row within tile / B row within n-tile
    const int koff = (lane >> 4) * 8;    // k offset of this lane's 8 contiguous elems

    const float* aptr = x  + (size_t)(m0 + cl) * C_DIM + koff;
    const short* bptr = Wb + (size_t)cl * C_DIM + koff;

    f32x4 acc[K_DIM];
    #pragma unroll
    for (int n = 0; n < K_DIM; ++n) acc[n] = (f32x4){0.f, 0.f, 0.f, 0.f};

    for (int q = 0; q < 8; ++q) {
        const int kb = wid * 8 + q;      // this wave's k-block
        f32x4 a0 = *(const f32x4*)(aptr + kb * 32);
        f32x4 a1 = *(const f32x4*)(aptr + kb * 32 + 4);
        s16x8 afr;
        afr[0] = f2bf(a0[0]); afr[1] = f2bf(a0[1]); afr[2] = f2bf(a0[2]); afr[3] = f2bf(a0[3]);
        afr[4] = f2bf(a1[0]); afr[5] = f2bf(a1[1]); afr[6] = f2bf(a1[2]); afr[7] = f2bf(a1[3]);
        #pragma unroll
        for (int nt = 0; nt < K_DIM; ++nt) {
            s16x8 bf = *(const s16x8*)(bptr + nt * 16 * C_DIM + kb * 32);
            acc[nt] = __builtin_amdgcn_mfma_f32_16x16x32_bf16(afr, bf, acc[nt], 0, 0, 0);
        }
    }

    // D layout: col=lane&15, row=(lane>>4)*4 + reg  [m89]
    const int r0 = (lane >> 4) * 4;
    #pragma unroll
    for (int nt = 0; nt < K_DIM; ++nt)
        #pragma unroll
        for (int j = 0; j < 4; ++j)
            sm[wid][r0 + j][nt * 16 + cl] = acc[nt][j];
    __syncthreads();

    // combine 4 k-partials + softmax over K=7: 256 tasks = 16 rows x 16 heads
    const int r = tid >> 4, h = tid & 15;
    float v[K_DIM];
    float mx = -1e30f;
    #pragma unroll
    for (int k = 0; k < K_DIM; ++k) {
        v[k] = sm[0][r][h * 7 + k] + sm[1][r][h * 7 + k]
             + sm[2][r][h * 7 + k] + sm[3][r][h * 7 + k];
        mx = fmaxf(mx, v[k]);
    }
    float s = 0.f;
    #pragma unroll
    for (int k = 0; k < K_DIM; ++k) { v[k] = __expf(v[k] - mx); s += v[k]; }
    const float inv = 1.f / s;
    unsigned short* wrow = wt + (size_t)(m0 + r) * HK + h * 7;
    #pragma unroll
    for (int k = 0; k < K_DIM; ++k) wrow[k] = (unsigned short)f2bf(v[k] * inv);
}

// ---------------- Kernel 2: causal dynamic conv (register rolling window) --------
// Block = (t-chunk of TT, batch b); 256 threads x float4 = all 1024 channels.
// Softmax weights staged to LDS (vector bf16x8 loads), broadcast-read.
__global__ __launch_bounds__(256) void k_conv(const float* __restrict__ x,
                                              const unsigned short* __restrict__ wt,
                                              const float* __restrict__ bias,
                                              float* __restrict__ out) {
    __shared__ float smw[TT][HK];
    const int tid = (int)threadIdx.x;
    const int b   = (int)blockIdx.y;
    const int t0  = (int)blockIdx.x * TT;

    // stage TT rows x 112 bf16 weights -> LDS f32 (224 x s16x8 chunks)
    if (tid < TT * 14) {
        const int row = tid / 14, seg = tid % 14;
        const unsigned short* p = wt + ((size_t)(t0 + row) * B_DIM + b) * HK + seg * 8;
        s16x8 wv = *(const s16x8*)p;
        #pragma unroll
        for (int j = 0; j < 8; ++j)
            smw[row][seg * 8 + j] = bf2f(((const unsigned short*)&wv)[j]);
    }

    const int c4 = tid * 4;
    const int h  = tid >> 4;
    const f32x4 bias4 = *(const f32x4*)(bias + c4);

    f32x4 win[6];
    #pragma unroll
    for (int k = 0; k < 6; ++k) {
        const int t = t0 - 6 + k;
        win[k] = (t >= 0) ? *(const f32x4*)(x + ((size_t)t * B_DIM + b) * C_DIM + c4)
                          : (f32x4){0.f, 0.f, 0.f, 0.f};
    }
    __syncthreads();

    #pragma unroll
    for (int tt = 0; tt < TT; ++tt) {
        const size_t row = (size_t)(t0 + tt) * B_DIM + b;
        const f32x4 xv = *(const f32x4*)(x + row * C_DIM + c4);
        const float* wr = &smw[tt][h * 7];

        f32x4 o = bias4;
        o += win[0] * wr[0];
        o += win[1] * wr[1];
        o += win[2] * wr[2];
        o += win[3] * wr[3];
        o += win[4] * wr[4];
        o += win[5] * wr[5];
        o += xv     * wr[6];
        *(f32x4*)(out + row * C_DIM + c4) = o;

        win[0] = win[1]; win[1] = win[2]; win[2] = win[3];
        win[3] = win[4]; win[4] = win[5]; win[5] = xv;
    }
}

extern "C" void kernel_launch(void* const* d_in, const int* in_sizes, int n_in,
                              void* d_out, int out_size, void* d_ws, size_t ws_size,
                              hipStream_t stream) {
    const float* x    = (const float*)d_in[0];
    const float* W    = (const float*)d_in[1];
    const float* bias = (const float*)d_in[2];
    float* out = (float*)d_out;

    short*          Wb = (short*)d_ws;                              // 229 KB bf16 W
    unsigned short* wt = (unsigned short*)((char*)d_ws + 262144);   // 1.84 MB bf16 weights

    k_cvtW  <<<56, 256, 0, stream>>>(W, Wb);
    k_logits<<<(T_DIM * B_DIM) / 16, 256, 0, stream>>>(x, Wb, wt);
    k_conv  <<<dim3(T_DIM / TT, B_DIM), 256, 0, stream>>>(x, wt, bias, out);
}